// Round 3
// baseline (176.555 us; speedup 1.0000x reference)
//
#include <hip/hip_runtime.h>

// 2-level 2D Haar DWT, fused. x: (96, 512, 512) fp32 (B*C=96 images).
// Each thread: one 4-col x 8-row input strip -> two vertically adjacent
// level-2 pixels + 4 rows x 2 cols of h1/v1/d1.
// Out layout (flat, reference return order): a2,h2,v2,d2 (each 96*128*128),
// then h1,v1,d1 (each 96*256*256).

#define KINV 0.7071067811865476f

typedef float v2f __attribute__((ext_vector_type(2)));   // clang-native, OK for nontemporal builtin
typedef float v4f __attribute__((ext_vector_type(4)));

__global__ __launch_bounds__(256) void haar2_fused_kernel(
    const float* __restrict__ x, float* __restrict__ out, int nimg)
{
    const int tid = blockIdx.x * blockDim.x + threadIdx.x;
    const int total = nimg << 13;       // nimg * 128 * 64
    if (tid >= total) return;

    const int c2  = tid & 127;          // level-2 col (lane-fast -> coalesced)
    const int rp  = (tid >> 7) & 63;    // level-2 row-pair
    const int img = tid >> 13;

    const float* xin = x + (size_t)img * (512 * 512);
    const int row0 = rp * 8;
    const int col0 = c2 * 4;

    // 8 independent float4 row loads (16B/lane, each fully coalesced).
    float p[8][4];
    #pragma unroll
    for (int k = 0; k < 8; ++k) {
        v4f v = *reinterpret_cast<const v4f*>(xin + (size_t)(row0 + k) * 512 + col0);
        p[k][0] = v.x; p[k][1] = v.y; p[k][2] = v.z; p[k][3] = v.w;
    }

    // Level 1: eight 2x2 quads (4 row-pairs x 2 col-pairs).
    float aa[4][2], da[4][2], ad[4][2], dd[4][2];
    #pragma unroll
    for (int i = 0; i < 4; ++i) {
        #pragma unroll
        for (int j = 0; j < 2; ++j) {
            const float p00 = p[2*i    ][2*j], p01 = p[2*i    ][2*j+1];
            const float p10 = p[2*i + 1][2*j], p11 = p[2*i + 1][2*j+1];
            // along W (last axis) first, then along H — exactly as reference
            const float sA = (p00 + p01) * KINV;
            const float sB = (p10 + p11) * KINV;
            const float dA = (p00 - p01) * KINV;
            const float dB = (p10 - p11) * KINV;
            aa[i][j] = (sA + sB) * KINV;   // cA1
            da[i][j] = (sA - sB) * KINV;   // cH1
            ad[i][j] = (dA + dB) * KINV;   // cV1
            dd[i][j] = (dA - dB) * KINV;   // cD1
        }
    }

    // Output section pointers.
    const size_t n2 = (size_t)nimg * 128 * 128;
    const size_t n1 = (size_t)nimg * 256 * 256;
    float* a2o = out;
    float* h2o = out + n2;
    float* v2o = out + 2 * n2;
    float* d2o = out + 3 * n2;
    float* h1o = out + 4 * n2;
    float* v1o = h1o + n1;
    float* d1o = h1o + 2 * n1;

    // Level-1 detail stores: nontemporal v2f (8B/lane, coalesced, streaming).
    const size_t img1 = (size_t)img * 256 * 256;
    #pragma unroll
    for (int i = 0; i < 4; ++i) {
        const size_t off = img1 + (size_t)(4 * rp + i) * 256 + 2 * c2;
        v2f h = {da[i][0], da[i][1]};
        v2f v = {ad[i][0], ad[i][1]};
        v2f d = {dd[i][0], dd[i][1]};
        __builtin_nontemporal_store(h, reinterpret_cast<v2f*>(h1o + off));
        __builtin_nontemporal_store(v, reinterpret_cast<v2f*>(v1o + off));
        __builtin_nontemporal_store(d, reinterpret_cast<v2f*>(d1o + off));
    }

    // Level 2: two output rows from the four aa row-pairs.
    #pragma unroll
    for (int h = 0; h < 2; ++h) {
        const int i0 = 2 * h;
        const float s0 = (aa[i0][0]     + aa[i0][1])     * KINV;
        const float d0 = (aa[i0][0]     - aa[i0][1])     * KINV;
        const float s1 = (aa[i0 + 1][0] + aa[i0 + 1][1]) * KINV;
        const float d1 = (aa[i0 + 1][0] - aa[i0 + 1][1]) * KINV;
        const size_t off2 = (size_t)img * 128 * 128 + (size_t)(2 * rp + h) * 128 + c2;
        __builtin_nontemporal_store((s0 + s1) * KINV, a2o + off2);
        __builtin_nontemporal_store((s0 - s1) * KINV, h2o + off2);
        __builtin_nontemporal_store((d0 + d1) * KINV, v2o + off2);
        __builtin_nontemporal_store((d0 - d1) * KINV, d2o + off2);
    }
}

extern "C" void kernel_launch(void* const* d_in, const int* in_sizes, int n_in,
                              void* d_out, int out_size, void* d_ws, size_t ws_size,
                              hipStream_t stream) {
    const float* x = (const float*)d_in[0];
    float* out = (float*)d_out;
    const int nimg = in_sizes[0] / (512 * 512);   // 32*3 = 96
    const int total = nimg << 13;                 // one thread per 4x8 strip
    const int block = 256;
    const int grid = (total + block - 1) / block; // 3072
    haar2_fused_kernel<<<grid, block, 0, stream>>>(x, out, nimg);
}

// Round 4
// 175.175 us; speedup vs baseline: 1.0079x; 1.0079x over previous
//
#include <hip/hip_runtime.h>

// 2-level 2D Haar DWT, fused, LDS-staged stores. x: (96, 512, 512) fp32.
// Block = 256 threads, covers one img x 16 input rows x 512 cols.
// Phase 1: thread (cx=t&127, ry=t>>7) owns 4 cols x 8 rows; perfectly
//   coalesced float4 loads; computes lvl1 quads + lvl2 pixels; stages
//   results in LDS.
// Phase 2: cooperative write-out, every store = contiguous float4/lane.
// Out layout: a2,h2,v2,d2 (each 96*128*128), then h1,v1,d1 (each 96*256*256).

#define KINV 0.7071067811865476f

typedef float v4f __attribute__((ext_vector_type(4)));
typedef float v2f __attribute__((ext_vector_type(2)));

__global__ __launch_bounds__(256) void haar2_fused_kernel(
    const float* __restrict__ x, float* __restrict__ out, int nimg)
{
    __shared__ float lds1[3][8][256];   // h1,v1,d1 block tile: 8 rows x 256 cols
    __shared__ float lds2[4][4][128];   // a2,h2,v2,d2 block tile: 4 rows x 128 cols

    const int t   = threadIdx.x;
    const int bid = blockIdx.x;
    const int by  = bid & 31;           // 32 row-blocks of 16 input rows
    const int img = bid >> 5;

    const int cx = t & 127;             // 4-col group (lane-fast -> coalesced)
    const int ry = t >> 7;              // 0..1: 8-row group within block

    const float* xin = x + (size_t)img * (512 * 512);
    const int row0 = by * 16 + ry * 8;
    const int col0 = cx * 4;

    // 8 independent float4 row loads (16B/lane, fully coalesced).
    float p[8][4];
    #pragma unroll
    for (int k = 0; k < 8; ++k) {
        v4f v = *reinterpret_cast<const v4f*>(xin + (size_t)(row0 + k) * 512 + col0);
        p[k][0] = v.x; p[k][1] = v.y; p[k][2] = v.z; p[k][3] = v.w;
    }

    // Level 1: 4 row-pairs x 2 col-pairs; stage details to LDS.
    float aa[4][2];
    #pragma unroll
    for (int i = 0; i < 4; ++i) {
        float da[2], ad[2], dd[2];
        #pragma unroll
        for (int j = 0; j < 2; ++j) {
            const float p00 = p[2*i    ][2*j], p01 = p[2*i    ][2*j+1];
            const float p10 = p[2*i + 1][2*j], p11 = p[2*i + 1][2*j+1];
            // along W first, then along H — exact reference op order
            const float sA = (p00 + p01) * KINV;
            const float sB = (p10 + p11) * KINV;
            const float dA = (p00 - p01) * KINV;
            const float dB = (p10 - p11) * KINV;
            aa[i][j] = (sA + sB) * KINV;
            da[j]    = (sA - sB) * KINV;   // cH1
            ad[j]    = (dA + dB) * KINV;   // cV1
            dd[j]    = (dA - dB) * KINV;   // cD1
        }
        const int lr = 4 * ry + i;
        // float2 LDS writes: lane stride 8B -> 2-way bank aliasing (free)
        *reinterpret_cast<v2f*>(&lds1[0][lr][2 * cx]) = (v2f){da[0], da[1]};
        *reinterpret_cast<v2f*>(&lds1[1][lr][2 * cx]) = (v2f){ad[0], ad[1]};
        *reinterpret_cast<v2f*>(&lds1[2][lr][2 * cx]) = (v2f){dd[0], dd[1]};
    }

    // Level 2 from aa quads; stage to LDS.
    #pragma unroll
    for (int h = 0; h < 2; ++h) {
        const int i0 = 2 * h;
        const float s0 = (aa[i0][0]     + aa[i0][1])     * KINV;
        const float d0 = (aa[i0][0]     - aa[i0][1])     * KINV;
        const float s1 = (aa[i0 + 1][0] + aa[i0 + 1][1]) * KINV;
        const float d1 = (aa[i0 + 1][0] - aa[i0 + 1][1]) * KINV;
        const int lr = 2 * ry + h;
        lds2[0][lr][cx] = (s0 + s1) * KINV;   // a2
        lds2[1][lr][cx] = (s0 - s1) * KINV;   // h2
        lds2[2][lr][cx] = (d0 + d1) * KINV;   // v2
        lds2[3][lr][cx] = (d0 - d1) * KINV;   // d2
    }

    __syncthreads();

    // Output section pointers.
    const size_t n2 = (size_t)nimg * 128 * 128;
    const size_t n1 = (size_t)nimg * 256 * 256;
    float* outs1[3] = { out + 4 * n2, out + 4 * n2 + n1, out + 4 * n2 + 2 * n1 }; // h1,v1,d1
    float* outs2[4] = { out, out + n2, out + 2 * n2, out + 3 * n2 };              // a2,h2,v2,d2

    // Phase 2a: level-1 details. Each array tile = 8 rows x 256 cols = 512 float4.
    // 256 threads -> 2 rounds per array; every store 16B/lane, wave covers a full
    // contiguous 1KB output row.
    const size_t img1 = (size_t)img * 256 * 256;
    #pragma unroll
    for (int arr = 0; arr < 3; ++arr) {
        #pragma unroll
        for (int r = 0; r < 2; ++r) {
            const int idx = r * 256 + t;        // 0..511 float4 index
            const int row = idx >> 6;           // 0..7
            const int c4  = idx & 63;           // 0..63
            v4f v = *reinterpret_cast<const v4f*>(&lds1[arr][row][4 * c4]);
            float* dst = outs1[arr] + img1 + (size_t)(8 * by + row) * 256 + 4 * c4;
            __builtin_nontemporal_store(v, reinterpret_cast<v4f*>(dst));
        }
    }

    // Phase 2b: level-2. 4 arrays x 128 float4 = 512 float4 -> 2 rounds.
    const size_t img2 = (size_t)img * 128 * 128;
    #pragma unroll
    for (int r = 0; r < 2; ++r) {
        const int idx = r * 256 + t;            // 0..511
        const int arr = idx >> 7;               // 0..3
        const int rem = idx & 127;
        const int row = rem >> 5;               // 0..3
        const int c4  = rem & 31;               // 0..31
        v4f v = *reinterpret_cast<const v4f*>(&lds2[arr][row][4 * c4]);
        float* dst = outs2[arr] + img2 + (size_t)(4 * by + row) * 128 + 4 * c4;
        __builtin_nontemporal_store(v, reinterpret_cast<v4f*>(dst));
    }
}

extern "C" void kernel_launch(void* const* d_in, const int* in_sizes, int n_in,
                              void* d_out, int out_size, void* d_ws, size_t ws_size,
                              hipStream_t stream) {
    const float* x = (const float*)d_in[0];
    float* out = (float*)d_out;
    const int nimg = in_sizes[0] / (512 * 512);   // 32*3 = 96
    const int grid = nimg * 32;                    // 32 row-blocks per image
    haar2_fused_kernel<<<grid, 256, 0, stream>>>(x, out, nimg);
}

// Round 5
// 174.574 us; speedup vs baseline: 1.0113x; 1.0034x over previous
//
#include <hip/hip_runtime.h>

// 2-level 2D Haar DWT, fused, PERSISTENT double-buffered kernel.
// x: (96, 512, 512) fp32. Thread owns fixed (r2,c2) 4x4 tile position and
// loops over 8 images (stride 12), prefetching tile i+1's loads before
// computing/storing tile i. Steady state: loads in flight while stores drain.
// Out layout: a2,h2,v2,d2 (each 96*128*128), then h1,v1,d1 (each 96*256*256).

#define KINV 0.7071067811865476f

typedef float v4f __attribute__((ext_vector_type(4)));
typedef float v2f __attribute__((ext_vector_type(2)));

#define IMG_STRIDE 12   // images advanced per iteration
#define NITER 8         // 96 / 12

__global__ __launch_bounds__(256) void haar2_fused_kernel(
    const float* __restrict__ x, float* __restrict__ out, int nimg)
{
    const int tid = blockIdx.x * blockDim.x + threadIdx.x;   // 0 .. 12*16384-1
    const int c2   = tid & 127;          // level-2 col (lane-fast -> coalesced)
    const int r2   = (tid >> 7) & 127;   // level-2 row
    const int img0 = tid >> 14;          // 0..11

    const int row0 = r2 * 4;
    const int col0 = c2 * 4;

    // Section pointers.
    const size_t n2 = (size_t)nimg * 128 * 128;
    const size_t n1 = (size_t)nimg * 256 * 256;
    float* a2o = out;
    float* h2o = out + n2;
    float* v2o = out + 2 * n2;
    float* d2o = out + 3 * n2;
    float* h1o = out + 4 * n2;
    float* v1o = h1o + n1;
    float* d1o = h1o + 2 * n1;

    const size_t in_base = (size_t)img0 * (512 * 512) + (size_t)row0 * 512 + col0;
    const size_t in_step = (size_t)IMG_STRIDE * 512 * 512;

    // Prologue: load tile for img0.
    v4f buf[2][4];
    #pragma unroll
    for (int k = 0; k < 4; ++k)
        buf[0][k] = *reinterpret_cast<const v4f*>(x + in_base + (size_t)k * 512);

    #pragma unroll
    for (int it = 0; it < NITER; ++it) {
        const int cur = it & 1;
        // Prefetch next tile FIRST (independent of current compute/stores).
        if (it + 1 < NITER) {
            const size_t nb = in_base + (size_t)(it + 1) * in_step;
            #pragma unroll
            for (int k = 0; k < 4; ++k)
                buf[cur ^ 1][k] = *reinterpret_cast<const v4f*>(x + nb + (size_t)k * 512);
        }

        const int img = img0 + it * IMG_STRIDE;
        float p[4][4];
        #pragma unroll
        for (int k = 0; k < 4; ++k) {
            p[k][0] = buf[cur][k].x; p[k][1] = buf[cur][k].y;
            p[k][2] = buf[cur][k].z; p[k][3] = buf[cur][k].w;
        }

        // Level 1: four 2x2 quads.
        float aa[2][2], da[2][2], ad[2][2], dd[2][2];
        #pragma unroll
        for (int i = 0; i < 2; ++i) {
            #pragma unroll
            for (int j = 0; j < 2; ++j) {
                const float p00 = p[2*i    ][2*j], p01 = p[2*i    ][2*j+1];
                const float p10 = p[2*i + 1][2*j], p11 = p[2*i + 1][2*j+1];
                // along W first, then along H — exact reference op order
                const float sA = (p00 + p01) * KINV;
                const float sB = (p10 + p11) * KINV;
                const float dA = (p00 - p01) * KINV;
                const float dB = (p10 - p11) * KINV;
                aa[i][j] = (sA + sB) * KINV;
                da[i][j] = (sA - sB) * KINV;   // cH1
                ad[i][j] = (dA + dB) * KINV;   // cV1
                dd[i][j] = (dA - dB) * KINV;   // cD1
            }
        }

        // Level-1 detail stores (float2/lane, coalesced across c2; cached so
        // memory-side L3 can absorb).
        const size_t img1 = (size_t)img * 256 * 256;
        #pragma unroll
        for (int i = 0; i < 2; ++i) {
            const size_t off = img1 + (size_t)(2 * r2 + i) * 256 + 2 * c2;
            *reinterpret_cast<v2f*>(h1o + off) = (v2f){da[i][0], da[i][1]};
            *reinterpret_cast<v2f*>(v1o + off) = (v2f){ad[i][0], ad[i][1]};
            *reinterpret_cast<v2f*>(d1o + off) = (v2f){dd[i][0], dd[i][1]};
        }

        // Level 2 from the aa quad.
        const float s0 = (aa[0][0] + aa[0][1]) * KINV;
        const float d0 = (aa[0][0] - aa[0][1]) * KINV;
        const float s1 = (aa[1][0] + aa[1][1]) * KINV;
        const float d1 = (aa[1][0] - aa[1][1]) * KINV;
        const size_t off2 = (size_t)img * 128 * 128 + (size_t)r2 * 128 + c2;
        a2o[off2] = (s0 + s1) * KINV;
        h2o[off2] = (s0 - s1) * KINV;
        v2o[off2] = (d0 + d1) * KINV;
        d2o[off2] = (d0 - d1) * KINV;
    }
}

extern "C" void kernel_launch(void* const* d_in, const int* in_sizes, int n_in,
                              void* d_out, int out_size, void* d_ws, size_t ws_size,
                              hipStream_t stream) {
    const float* x = (const float*)d_in[0];
    float* out = (float*)d_out;
    const int nimg = in_sizes[0] / (512 * 512);       // 96
    const int total_threads = IMG_STRIDE * 128 * 128; // 196608 threads
    const int block = 256;
    const int grid = total_threads / block;           // 768 blocks (3/CU)
    haar2_fused_kernel<<<grid, block, 0, stream>>>(x, out, nimg);
}